// Round 4
// baseline (16683.084 us; speedup 1.0000x reference)
//
#include <hip/hip_runtime.h>
#include <math.h>

// TemporalDecoder round 4: persistent kernel, REGULAR launch (cooperative launch
// is not graph-capturable -> R3's kernel never ran). 144KB static LDS forces
// 1 WG/CU; grid=256=#CUs guarantees co-residency for the hand-rolled grid barrier.
// - 256 WGs x 256 thr. Half0 (WG 0..127) = layer0 + fc; half1 = layer1.
// - Weights f16 hi + (2^11-scaled) f16 lo, pre-arranged in MFMA B-fragment order,
//   loaded once into LDS and reused for all 160 steps.
// - Encode: layer-pipelined, 129 barriers. Decode: fc->L0->L1 serial (94 barriers).

#define BB 256
#define SS 128
#define HH 512
#define NSTEPS 32

typedef __attribute__((ext_vector_type(8))) _Float16 f16x8;
typedef __attribute__((ext_vector_type(4))) float f32x4;

#define LO_SCALE 2048.0f
#define LO_INV   (1.0f / 2048.0f)

// ---------------- weight split kernels (fp32 -> f16 hi/lo, fragment order) ----
__global__ __launch_bounds__(256) void wsplit_layers(
    const float* __restrict__ W_ih, const float* __restrict__ W_hh,
    ushort* __restrict__ wf0, ushort* __restrict__ wf1)
{
    int f = blockIdx.x * 256 + threadIdx.x;      // 0..524287
    int L = f >> 18;
    int t = f & 262143;
    int lane = t & 63;
    int kfg = (t >> 6) & 31;
    int nfrag = t >> 11;                         // 0..127
    int nloc = (nfrag & 1) * 16 + (lane & 15);
    int g = nloc & 3, hc = nloc >> 2;
    int n_W = g * 512 + (nfrag >> 1) * 8 + hc;
    int mat = kfg >> 4;
    int klocal = (kfg & 15) * 32 + (lane >> 4) * 8;
    const float* src = (mat ? W_hh : W_ih) + (size_t)L * (2048 * 512)
                       + (size_t)n_W * 512 + klocal;
    float4 a = *(const float4*)src;
    float4 b = *(const float4*)(src + 4);
    float v[8] = {a.x, a.y, a.z, a.w, b.x, b.y, b.z, b.w};
    union { _Float16 h[8]; uint4 u; } Hi, Lo;
    #pragma unroll
    for (int j = 0; j < 8; ++j) {
        Hi.h[j] = (_Float16)v[j];
        Lo.h[j] = (_Float16)((v[j] - (float)Hi.h[j]) * LO_SCALE);
    }
    ushort* dst = L ? wf1 : wf0;
    size_t b0 = (((size_t)nfrag * 2 + 0) * 32 + kfg) * 512 + lane * 8;
    size_t b1 = (((size_t)nfrag * 2 + 1) * 32 + kfg) * 512 + lane * 8;
    *(uint4*)(dst + b0) = Hi.u;
    *(uint4*)(dst + b1) = Lo.u;
}

__global__ __launch_bounds__(256) void wsplit_out(
    const float* __restrict__ W_out, ushort* __restrict__ wfO)
{
    int f = blockIdx.x * 256 + threadIdx.x;      // 0..32767
    int lane = f & 63;
    int kfg = (f >> 6) & 15;
    int nfrag = f >> 10;                         // 0..31
    int n_W = nfrag * 16 + (lane & 15);
    int klocal = kfg * 32 + (lane >> 4) * 8;
    const float* src = W_out + (size_t)n_W * 512 + klocal;
    float4 a = *(const float4*)src;
    float4 b = *(const float4*)(src + 4);
    float v[8] = {a.x, a.y, a.z, a.w, b.x, b.y, b.z, b.w};
    union { _Float16 h[8]; uint4 u; } Hi, Lo;
    #pragma unroll
    for (int j = 0; j < 8; ++j) {
        Hi.h[j] = (_Float16)v[j];
        Lo.h[j] = (_Float16)((v[j] - (float)Hi.h[j]) * LO_SCALE);
    }
    size_t b0 = (((size_t)nfrag * 2 + 0) * 16 + kfg) * 512 + lane * 8;
    size_t b1 = (((size_t)nfrag * 2 + 1) * 16 + kfg) * 512 + lane * 8;
    *(uint4*)(wfO + b0) = Hi.u;
    *(uint4*)(wfO + b1) = Lo.u;
}

// ---------------- grid barrier (monotonic, hierarchical) ----------------------
__device__ __forceinline__ void gridbar(unsigned* bar, unsigned phase)
{
    __syncthreads();
    __threadfence();
    if (threadIdx.x == 0) {
        const int grp = blockIdx.x & 7;
        unsigned* lc = bar + 16 + 16 * grp;      // 64B-padded per-group counters
        unsigned* gc = bar;
        unsigned old = __hip_atomic_fetch_add(lc, 1u, __ATOMIC_ACQ_REL,
                                              __HIP_MEMORY_SCOPE_AGENT);
        if (old == phase * 32u - 1u)             // last of the 32 WGs in this group
            __hip_atomic_fetch_add(gc, 1u, __ATOMIC_ACQ_REL,
                                   __HIP_MEMORY_SCOPE_AGENT);
        while (__hip_atomic_load(gc, __ATOMIC_ACQUIRE,
                                 __HIP_MEMORY_SCOPE_AGENT) < phase * 8u)
            __builtin_amdgcn_s_sleep(2);
    }
    __syncthreads();
}

// ---------------- LSTM cell (one layer, M=128 x N=32 gate-cols, K=1024) -------
static __device__ __forceinline__ void run_cell(
    const int tid, const int mblk, const int hcblk,
    const void* Asrc, const size_t ldA, const bool cvtA,
    const ushort* __restrict__ Hprev,
    ushort (*sW)[2][32][512], ushort (*sA)[64],
    const float bias, float* __restrict__ Cst, ushort* __restrict__ Hout)
{
    const int lane = tid & 63, wid = tid >> 6;
    const int wm = wid >> 1, wn = wid & 1;
    const int lr = lane & 15, lq = lane >> 4;

    f32x4 acch[4], accl[4];
    #pragma unroll
    for (int i = 0; i < 4; ++i) {
        acch[i] = (f32x4){bias, bias, bias, bias};
        accl[i] = (f32x4){0.f, 0.f, 0.f, 0.f};
    }

    const int srow = tid >> 1;               // 0..127
    const int cbase = (tid & 1) * 4;         // chunk base (chunks of 8 f16)
    float4 fr[8];
    uint4 ur[4];
    bool cvtCur = false, cvtNext = false;

    auto do_load = [&](int it, bool& isCvt) {
        const bool ph0 = (it < 8);
        const int k0 = (it & 7) * 64;
        isCvt = ph0 && cvtA;
        if (isCvt) {
            const float* s = (const float*)Asrc
                + (size_t)(mblk * 128 + srow) * ldA + k0 + cbase * 8;
            #pragma unroll
            for (int c = 0; c < 4; ++c) {
                fr[2 * c]     = *(const float4*)(s + c * 8);
                fr[2 * c + 1] = *(const float4*)(s + c * 8 + 4);
            }
        } else {
            const ushort* s = ph0
                ? ((const ushort*)Asrc + (size_t)(mblk * 128 + srow) * ldA + k0 + cbase * 8)
                : (Hprev + (size_t)(mblk * 128 + srow) * 512 + k0 + cbase * 8);
            #pragma unroll
            for (int c = 0; c < 4; ++c) ur[c] = *(const uint4*)(s + c * 8);
        }
    };
    auto do_write = [&](bool isCvt) {
        #pragma unroll
        for (int c = 0; c < 4; ++c) {
            const int cg = cbase + c;
            ushort* d = &sA[srow][(cg ^ (srow & 7)) * 8];
            if (isCvt) {
                union { _Float16 h[8]; uint4 u; } P;
                const float4 f0 = fr[2 * c], f1 = fr[2 * c + 1];
                P.h[0] = (_Float16)f0.x; P.h[1] = (_Float16)f0.y;
                P.h[2] = (_Float16)f0.z; P.h[3] = (_Float16)f0.w;
                P.h[4] = (_Float16)f1.x; P.h[5] = (_Float16)f1.y;
                P.h[6] = (_Float16)f1.z; P.h[7] = (_Float16)f1.w;
                *(uint4*)d = P.u;
            } else {
                *(uint4*)d = ur[c];
            }
        }
    };

    do_load(0, cvtCur);
    #pragma unroll 1
    for (int it = 0; it < 16; ++it) {
        __syncthreads();                      // sA free (prev compute done)
        do_write(cvtCur);
        if (it < 15) do_load(it + 1, cvtNext);   // in flight under compute
        __syncthreads();                      // sA ready
        #pragma unroll
        for (int kf = 0; kf < 2; ++kf) {
            const int kfg = it * 2 + kf;
            const f16x8 bh = *(const f16x8*)&sW[wn][0][kfg][lane * 8];
            const f16x8 bl = *(const f16x8*)&sW[wn][1][kfg][lane * 8];
            #pragma unroll
            for (int mf = 0; mf < 4; ++mf) {
                const int row = wm * 64 + mf * 16 + lr;
                const int cg = kf * 4 + lq;
                const f16x8 a = *(const f16x8*)&sA[row][(cg ^ (row & 7)) * 8];
                acch[mf] = __builtin_amdgcn_mfma_f32_16x16x32_f16(a, bh, acch[mf], 0, 0, 0);
                accl[mf] = __builtin_amdgcn_mfma_f32_16x16x32_f16(a, bl, accl[mf], 0, 0, 0);
            }
        }
        cvtCur = cvtNext;
    }

    // epilogue: gather i,f,g,o across the 4-lane group, apply cell
    const int nloc = wn * 16 + lr;
    const int g = nloc & 3, hc = nloc >> 2;
    const int hcol = hcblk * 8 + hc;
    #pragma unroll
    for (int mf = 0; mf < 4; ++mf) {
        #pragma unroll
        for (int j = 0; j < 4; ++j) {
            float v = acch[mf][j] + accl[mf][j] * LO_INV;
            float s1 = __shfl_xor(v, 1, 64);
            float s2 = __shfl_xor(v, 2, 64);
            float s3 = __shfl_xor(v, 3, 64);
            float sel0 = v;
            auto selk = [&](int k) {
                return (k == 0) ? sel0 : (k == 1) ? s1 : (k == 2) ? s2 : s3;
            };
            float pi = selk(g), pf = selk(g ^ 1), pg = selk(g ^ 2), po = selk(g ^ 3);
            int row = mblk * 128 + wm * 64 + mf * 16 + lq * 4 + j;
            size_t idx = (size_t)row * 512 + hcol;
            float ig = 1.f / (1.f + __expf(-pi));
            float fg = 1.f / (1.f + __expf(-pf));
            float e2g = __expf(2.f * fminf(fmaxf(pg, -20.f), 20.f));
            float gg = (e2g - 1.f) / (e2g + 1.f);
            float og = 1.f / (1.f + __expf(-po));
            float cn = fg * Cst[idx] + ig * gg;
            float e2c = __expf(2.f * fminf(fmaxf(cn, -20.f), 20.f));
            float th = (e2c - 1.f) / (e2c + 1.f);
            float hn = og * th;
            if (g == 0) {
                Cst[idx] = cn;
                union { _Float16 h; ushort u; } P;
                P.h = (_Float16)hn;
                Hout[idx] = P.u;
            }
        }
    }
}

// ---------------- fc: pred = h1 @ Wout^T + b_out (half0 WGs only) -------------
static __device__ __forceinline__ void run_fc(
    const int tid, const int w,
    const ushort* __restrict__ h1, const ushort* __restrict__ wfO,
    const float* __restrict__ b_out,
    ushort* __restrict__ pred, float* __restrict__ out, const int s)
{
    const int lane = tid & 63, wid = tid >> 6;
    const int wm = wid >> 1, wn = wid & 1;
    const int lr = lane & 15, lq = lane >> 4;
    const int fm = w & 7, fn = w >> 3;        // 8 m-blocks x 16 n-blocks
    const int nfrag = fn * 2 + wn;
    const int col = nfrag * 16 + lr;
    const int arow = fm * 32 + wm * 16 + lr;

    float bv = b_out[col];
    f32x4 acch = (f32x4){bv, bv, bv, bv};
    f32x4 accl = (f32x4){0.f, 0.f, 0.f, 0.f};
    #pragma unroll 4
    for (int kfg = 0; kfg < 16; ++kfg) {
        const f16x8 a = *(const f16x8*)&h1[(size_t)arow * 512 + kfg * 32 + lq * 8];
        const f16x8 bh = *(const f16x8*)&wfO[(((size_t)nfrag * 2 + 0) * 16 + kfg) * 512 + lane * 8];
        const f16x8 bl = *(const f16x8*)&wfO[(((size_t)nfrag * 2 + 1) * 16 + kfg) * 512 + lane * 8];
        acch = __builtin_amdgcn_mfma_f32_16x16x32_f16(a, bh, acch, 0, 0, 0);
        accl = __builtin_amdgcn_mfma_f32_16x16x32_f16(a, bl, accl, 0, 0, 0);
    }
    #pragma unroll
    for (int j = 0; j < 4; ++j) {
        float v = acch[j] + accl[j] * LO_INV;
        int row = fm * 32 + wm * 16 + lq * 4 + j;
        union { _Float16 h; ushort u; } P;
        P.h = (_Float16)v;
        pred[(size_t)row * 512 + col] = P.u;
        out[(size_t)row * (NSTEPS * 512) + (size_t)s * 512 + col] = v;
    }
}

// ---------------- persistent kernel ------------------------------------------
__global__ __launch_bounds__(256, 1) void persist(
    const float* __restrict__ x,
    const ushort* __restrict__ wf0, const ushort* __restrict__ wf1,
    const ushort* __restrict__ wfO,
    const float* __restrict__ b_ih, const float* __restrict__ b_hh,
    const float* __restrict__ b_out,
    ushort* h0a, ushort* h0b, ushort* h1a, ushort* h1b,
    ushort* pred, float* c0, float* c1,
    float* out, unsigned* bar)
{
    __shared__ ushort sW[2][2][32][512];      // 128KB: [wn][prec][kfg][lane*8]
    __shared__ ushort sA[128][64];            // 16KB, XOR-swizzled chunks

    const int tid = threadIdx.x;
    const int blk = blockIdx.x;
    const int half = blk >> 7;
    const int w = blk & 127;
    const int mblk = w >> 6, hcblk = w & 63;

    {   // load this WG's weight slice (128KB, contiguous in the frag array)
        const uint4* srcv = (const uint4*)((half ? wf1 : wf0) + (size_t)hcblk * 65536);
        uint4* dstv = (uint4*)&sW[0][0][0][0];
        #pragma unroll 1
        for (int i = tid; i < 8192; i += 256) dstv[i] = srcv[i];
    }
    const int lane = tid & 63, wid = tid >> 6, wn = wid & 1;
    const int nloc = wn * 16 + (lane & 15);
    const int g = nloc & 3, hc = nloc >> 2;
    const int gcol = g * 512 + hcblk * 8 + hc;
    const float bias = b_ih[half * 2048 + gcol] + b_hh[half * 2048 + gcol];
    __syncthreads();

    ushort* h0buf[2] = {h0a, h0b};
    ushort* h1buf[2] = {h1a, h1b};
    unsigned nbar = 0;

    // ---- encode: 129 phases, layer-pipelined ----
    #pragma unroll 1
    for (int p = 0; p <= SS; ++p) {
        if (half == 0) {
            if (p < SS)
                run_cell(tid, mblk, hcblk, x + (size_t)p * 512, (size_t)(SS * 512), true,
                         h0buf[p & 1], sW, sA, bias, c0, h0buf[(p + 1) & 1]);
        } else {
            if (p >= 1) {
                int q = p - 1;
                run_cell(tid, mblk, hcblk, h0buf[p & 1], 512, false,
                         h1buf[q & 1], sW, sA, bias, c1, h1buf[(q + 1) & 1]);
            }
        }
        gridbar(bar, ++nbar);
    }
    int h0cur = 0, h1cur = 0;

    // ---- decode: fc -> L0 -> L1 serial ----
    #pragma unroll 1
    for (int s = 0; s < NSTEPS; ++s) {
        if (half == 0) run_fc(tid, w, h1buf[h1cur], wfO, b_out, pred, out, s);
        gridbar(bar, ++nbar);
        if (s == NSTEPS - 1) break;
        if (half == 0)
            run_cell(tid, mblk, hcblk, pred, 512, false,
                     h0buf[h0cur], sW, sA, bias, c0, h0buf[h0cur ^ 1]);
        gridbar(bar, ++nbar);
        h0cur ^= 1;
        if (half == 1)
            run_cell(tid, mblk, hcblk, h0buf[h0cur], 512, false,
                     h1buf[h1cur], sW, sA, bias, c1, h1buf[h1cur ^ 1]);
        gridbar(bar, ++nbar);
        h1cur ^= 1;
    }
}

// ---------------- host ---------------------------------------------------------
extern "C" void kernel_launch(void* const* d_in, const int* in_sizes, int n_in,
                              void* d_out, int out_size, void* d_ws, size_t ws_size,
                              hipStream_t stream)
{
    const float* x     = (const float*)d_in[0];
    const float* W_ih  = (const float*)d_in[1];
    const float* W_hh  = (const float*)d_in[2];
    const float* b_ih  = (const float*)d_in[3];
    const float* b_hh  = (const float*)d_in[4];
    const float* W_out = (const float*)d_in[5];
    const float* b_out = (const float*)d_in[6];
    float* out = (float*)d_out;
    (void)in_sizes; (void)n_in; (void)out_size; (void)ws_size;

    char* ws = (char*)d_ws;
    ushort* h0a  = (ushort*)(ws + 0);
    ushort* h0b  = (ushort*)(ws + 262144);
    ushort* h1a  = (ushort*)(ws + 524288);
    ushort* h1b  = (ushort*)(ws + 786432);
    ushort* pred = (ushort*)(ws + 1048576);
    float*  c0   = (float*)(ws + 1310720);
    float*  c1   = (float*)(ws + 1835008);
    unsigned* bar = (unsigned*)(ws + 2359296);
    const size_t ZBYTES = 2360320;            // states + barrier counters (1KB)
    ushort* wf0 = (ushort*)(ws + 2360320);
    ushort* wf1 = (ushort*)(ws + 2360320 + 8388608);
    ushort* wfO = (ushort*)(ws + 2360320 + 2 * 8388608);
    // total ws use ≈ 20.2 MB

    hipMemsetAsync(d_ws, 0, ZBYTES, stream);
    wsplit_layers<<<2048, 256, 0, stream>>>(W_ih, W_hh, wf0, wf1);
    wsplit_out<<<128, 256, 0, stream>>>(W_out, wfO);

    // Regular launch: 144KB LDS -> 1 WG/CU; grid 256 = #CUs -> all co-resident.
    persist<<<dim3(256), dim3(256), 0, stream>>>(
        x, wf0, wf1, wfO, b_ih, b_hh, b_out,
        h0a, h0b, h1a, h1b, pred, c0, c1, out, bar);
}

// Round 5
// 6209.708 us; speedup vs baseline: 2.6866x; 2.6866x over previous
//
#include <hip/hip_runtime.h>
#include <math.h>

// TemporalDecoder round 5: persistent kernel with TARGETED cross-XCD coherence.
// R4 failed perf-wise because __threadfence (wbL2) + ACQUIRE polling (invL2)
// nuked every XCD's L2 ~every 130 cycles. Now: all cross-WG state (h0/h1/pred)
// moves via RELAXED agent-scope atomics (LLC-coherent, NO cache maintenance);
// barrier = relaxed fetch_add + relaxed poll + s_sleep. c-state lives in LDS.

#define BB 256
#define SS 128
#define HH 512
#define NSTEPS 32

typedef __attribute__((ext_vector_type(8))) _Float16 f16x8;
typedef __attribute__((ext_vector_type(4))) float f32x4;

#define LO_SCALE 2048.0f
#define LO_INV   (1.0f / 2048.0f)
#define AGENT __HIP_MEMORY_SCOPE_AGENT

__device__ __forceinline__ uint2 ld_agent_u2(const uint2* p) {
    return __hip_atomic_load(p, __ATOMIC_RELAXED, AGENT);
}
__device__ __forceinline__ void st_agent_h(ushort* p, ushort v) {
    __hip_atomic_store(p, v, __ATOMIC_RELAXED, AGENT);
}

// ---------------- weight split kernels (fp32 -> f16 hi/lo, fragment order) ----
__global__ __launch_bounds__(256) void wsplit_layers(
    const float* __restrict__ W_ih, const float* __restrict__ W_hh,
    ushort* __restrict__ wf0, ushort* __restrict__ wf1)
{
    int f = blockIdx.x * 256 + threadIdx.x;      // 0..524287
    int L = f >> 18;
    int t = f & 262143;
    int lane = t & 63;
    int kfg = (t >> 6) & 31;
    int nfrag = t >> 11;                         // 0..127
    int nloc = (nfrag & 1) * 16 + (lane & 15);
    int g = nloc & 3, hc = nloc >> 2;
    int n_W = g * 512 + (nfrag >> 1) * 8 + hc;
    int mat = kfg >> 4;
    int klocal = (kfg & 15) * 32 + (lane >> 4) * 8;
    const float* src = (mat ? W_hh : W_ih) + (size_t)L * (2048 * 512)
                       + (size_t)n_W * 512 + klocal;
    float4 a = *(const float4*)src;
    float4 b = *(const float4*)(src + 4);
    float v[8] = {a.x, a.y, a.z, a.w, b.x, b.y, b.z, b.w};
    union { _Float16 h[8]; uint4 u; } Hi, Lo;
    #pragma unroll
    for (int j = 0; j < 8; ++j) {
        Hi.h[j] = (_Float16)v[j];
        Lo.h[j] = (_Float16)((v[j] - (float)Hi.h[j]) * LO_SCALE);
    }
    ushort* dst = L ? wf1 : wf0;
    size_t b0 = (((size_t)nfrag * 2 + 0) * 32 + kfg) * 512 + lane * 8;
    size_t b1 = (((size_t)nfrag * 2 + 1) * 32 + kfg) * 512 + lane * 8;
    *(uint4*)(dst + b0) = Hi.u;
    *(uint4*)(dst + b1) = Lo.u;
}

__global__ __launch_bounds__(256) void wsplit_out(
    const float* __restrict__ W_out, ushort* __restrict__ wfO)
{
    int f = blockIdx.x * 256 + threadIdx.x;      // 0..32767
    int lane = f & 63;
    int kfg = (f >> 6) & 15;
    int nfrag = f >> 10;                         // 0..31
    int n_W = nfrag * 16 + (lane & 15);
    int klocal = kfg * 32 + (lane >> 4) * 8;
    const float* src = W_out + (size_t)n_W * 512 + klocal;
    float4 a = *(const float4*)src;
    float4 b = *(const float4*)(src + 4);
    float v[8] = {a.x, a.y, a.z, a.w, b.x, b.y, b.z, b.w};
    union { _Float16 h[8]; uint4 u; } Hi, Lo;
    #pragma unroll
    for (int j = 0; j < 8; ++j) {
        Hi.h[j] = (_Float16)v[j];
        Lo.h[j] = (_Float16)((v[j] - (float)Hi.h[j]) * LO_SCALE);
    }
    size_t b0 = (((size_t)nfrag * 2 + 0) * 16 + kfg) * 512 + lane * 8;
    size_t b1 = (((size_t)nfrag * 2 + 1) * 16 + kfg) * 512 + lane * 8;
    *(uint4*)(wfO + b0) = Hi.u;
    *(uint4*)(wfO + b1) = Lo.u;
}

// ---------------- grid barrier (monotonic, hierarchical, ALL RELAXED) ---------
__device__ __forceinline__ void gridbar(unsigned* bar, unsigned phase)
{
    __syncthreads();   // drains each wave's vmcnt (stores complete) + WG sync
    if (threadIdx.x == 0) {
        const int grp = blockIdx.x & 7;
        unsigned* lc = bar + 16 + 16 * grp;      // 64B-padded per-group counters
        unsigned* gc = bar;
        unsigned old = __hip_atomic_fetch_add(lc, 1u, __ATOMIC_RELAXED, AGENT);
        if (old == phase * 32u - 1u)             // last of the 32 WGs in this group
            __hip_atomic_fetch_add(gc, 1u, __ATOMIC_RELAXED, AGENT);
        while (__hip_atomic_load(gc, __ATOMIC_RELAXED, AGENT) < phase * 8u)
            __builtin_amdgcn_s_sleep(1);
    }
    __syncthreads();   // consumers' loads cannot start before this
}

// ---------------- LSTM cell (one layer, M=128 x N=32 gate-cols, K=1024) -------
static __device__ __forceinline__ void run_cell(
    const int tid, const int mblk, const int hcblk,
    const void* Asrc, const size_t ldA, const bool cvtA,
    const ushort* __restrict__ Hprev,
    ushort (*sW)[2][32][512], ushort (*sA)[64], float (*cL)[8],
    const float bias, ushort* __restrict__ Hout)
{
    const int lane = tid & 63, wid = tid >> 6;
    const int wm = wid >> 1, wn = wid & 1;
    const int lr = lane & 15, lq = lane >> 4;

    f32x4 acch[4], accl[4];
    #pragma unroll
    for (int i = 0; i < 4; ++i) {
        acch[i] = (f32x4){bias, bias, bias, bias};
        accl[i] = (f32x4){0.f, 0.f, 0.f, 0.f};
    }

    const int srow = tid >> 1;               // 0..127
    const int cbase = (tid & 1) * 4;         // chunk base (chunks of 8 f16)
    float4 fr[8];
    uint2 ur[8];
    bool cvtCur = false, cvtNext = false;

    auto do_load = [&](int it, bool& isCvt) {
        const bool ph0 = (it < 8);
        const int k0 = (it & 7) * 64;
        isCvt = ph0 && cvtA;
        if (isCvt) {
            const float* s = (const float*)Asrc
                + (size_t)(mblk * 128 + srow) * ldA + k0 + cbase * 8;
            #pragma unroll
            for (int c = 0; c < 4; ++c) {
                fr[2 * c]     = *(const float4*)(s + c * 8);
                fr[2 * c + 1] = *(const float4*)(s + c * 8 + 4);
            }
        } else {
            const ushort* s = ph0
                ? ((const ushort*)Asrc + (size_t)(mblk * 128 + srow) * ldA + k0 + cbase * 8)
                : (Hprev + (size_t)(mblk * 128 + srow) * 512 + k0 + cbase * 8);
            const uint2* s2 = (const uint2*)s;
            #pragma unroll
            for (int c = 0; c < 8; ++c) ur[c] = ld_agent_u2(s2 + c);
        }
    };
    auto do_write = [&](bool isCvt) {
        #pragma unroll
        for (int c = 0; c < 4; ++c) {
            const int cg = cbase + c;
            ushort* d = &sA[srow][(cg ^ (srow & 7)) * 8];
            if (isCvt) {
                union { _Float16 h[8]; uint4 u; } P;
                const float4 f0 = fr[2 * c], f1 = fr[2 * c + 1];
                P.h[0] = (_Float16)f0.x; P.h[1] = (_Float16)f0.y;
                P.h[2] = (_Float16)f0.z; P.h[3] = (_Float16)f0.w;
                P.h[4] = (_Float16)f1.x; P.h[5] = (_Float16)f1.y;
                P.h[6] = (_Float16)f1.z; P.h[7] = (_Float16)f1.w;
                *(uint4*)d = P.u;
            } else {
                uint4 wv;
                wv.x = ur[2 * c].x;     wv.y = ur[2 * c].y;
                wv.z = ur[2 * c + 1].x; wv.w = ur[2 * c + 1].y;
                *(uint4*)d = wv;
            }
        }
    };

    do_load(0, cvtCur);
    #pragma unroll 1
    for (int it = 0; it < 16; ++it) {
        __syncthreads();                      // sA free (prev compute done)
        do_write(cvtCur);
        if (it < 15) do_load(it + 1, cvtNext);   // in flight under compute
        __syncthreads();                      // sA ready
        #pragma unroll
        for (int kf = 0; kf < 2; ++kf) {
            const int kfg = it * 2 + kf;
            const f16x8 bh = *(const f16x8*)&sW[wn][0][kfg][lane * 8];
            const f16x8 bl = *(const f16x8*)&sW[wn][1][kfg][lane * 8];
            #pragma unroll
            for (int mf = 0; mf < 4; ++mf) {
                const int row = wm * 64 + mf * 16 + lr;
                const int cg = kf * 4 + lq;
                const f16x8 a = *(const f16x8*)&sA[row][(cg ^ (row & 7)) * 8];
                acch[mf] = __builtin_amdgcn_mfma_f32_16x16x32_f16(a, bh, acch[mf], 0, 0, 0);
                accl[mf] = __builtin_amdgcn_mfma_f32_16x16x32_f16(a, bl, accl[mf], 0, 0, 0);
            }
        }
        cvtCur = cvtNext;
    }

    // epilogue: gather i,f,g,o across the 4-lane group, apply cell
    const int nloc = wn * 16 + lr;
    const int g = nloc & 3, hc = nloc >> 2;
    const int hcol = hcblk * 8 + hc;
    #pragma unroll
    for (int mf = 0; mf < 4; ++mf) {
        #pragma unroll
        for (int j = 0; j < 4; ++j) {
            float v = acch[mf][j] + accl[mf][j] * LO_INV;
            float s1 = __shfl_xor(v, 1, 64);
            float s2 = __shfl_xor(v, 2, 64);
            float s3 = __shfl_xor(v, 3, 64);
            float sel0 = v;
            auto selk = [&](int k) {
                return (k == 0) ? sel0 : (k == 1) ? s1 : (k == 2) ? s2 : s3;
            };
            float pi = selk(g), pf = selk(g ^ 1), pg = selk(g ^ 2), po = selk(g ^ 3);
            int rloc = wm * 64 + mf * 16 + lq * 4 + j;       // 0..127 in-WG row
            int row = mblk * 128 + rloc;
            float ig = 1.f / (1.f + __expf(-pi));
            float fg = 1.f / (1.f + __expf(-pf));
            float e2g = __expf(2.f * fminf(fmaxf(pg, -20.f), 20.f));
            float gg = (e2g - 1.f) / (e2g + 1.f);
            float og = 1.f / (1.f + __expf(-po));
            if (g == 0) {
                float cn = fg * cL[rloc][hc & 7] + ig * gg;
                cL[rloc][hc & 7] = cn;
                float e2c = __expf(2.f * fminf(fmaxf(cn, -20.f), 20.f));
                float th = (e2c - 1.f) / (e2c + 1.f);
                float hn = og * th;
                union { _Float16 h; ushort u; } P;
                P.h = (_Float16)hn;
                st_agent_h(&Hout[(size_t)row * 512 + hcol], P.u);
            }
        }
    }
}

// ---------------- fc: pred = h1 @ Wout^T + b_out (half0 WGs only) -------------
static __device__ __forceinline__ void run_fc(
    const int tid, const int w,
    const ushort* __restrict__ h1, const ushort* __restrict__ wfO,
    const float* __restrict__ b_out,
    ushort* __restrict__ pred, float* __restrict__ out, const int s)
{
    const int lane = tid & 63, wid = tid >> 6;
    const int wm = wid >> 1, wn = wid & 1;
    const int lr = lane & 15, lq = lane >> 4;
    const int fm = w & 7, fn = w >> 3;        // 8 m-blocks x 16 n-blocks
    const int nfrag = fn * 2 + wn;
    const int col = nfrag * 16 + lr;
    const int arow = fm * 32 + wm * 16 + lr;

    float bv = b_out[col];
    f32x4 acch = (f32x4){bv, bv, bv, bv};
    f32x4 accl = (f32x4){0.f, 0.f, 0.f, 0.f};

    uint2 au[32];
    #pragma unroll
    for (int kfg = 0; kfg < 16; ++kfg) {
        const uint2* s = (const uint2*)&h1[(size_t)arow * 512 + kfg * 32 + lq * 8];
        au[2 * kfg]     = ld_agent_u2(s);
        au[2 * kfg + 1] = ld_agent_u2(s + 1);
    }
    #pragma unroll
    for (int kfg = 0; kfg < 16; ++kfg) {
        union { uint2 u[2]; f16x8 v; } A;
        A.u[0] = au[2 * kfg]; A.u[1] = au[2 * kfg + 1];
        const f16x8 bh = *(const f16x8*)&wfO[(((size_t)nfrag * 2 + 0) * 16 + kfg) * 512 + lane * 8];
        const f16x8 bl = *(const f16x8*)&wfO[(((size_t)nfrag * 2 + 1) * 16 + kfg) * 512 + lane * 8];
        acch = __builtin_amdgcn_mfma_f32_16x16x32_f16(A.v, bh, acch, 0, 0, 0);
        accl = __builtin_amdgcn_mfma_f32_16x16x32_f16(A.v, bl, accl, 0, 0, 0);
    }
    #pragma unroll
    for (int j = 0; j < 4; ++j) {
        float v = acch[j] + accl[j] * LO_INV;
        int row = fm * 32 + wm * 16 + lq * 4 + j;
        union { _Float16 h; ushort u; } P;
        P.h = (_Float16)v;
        st_agent_h(&pred[(size_t)row * 512 + col], P.u);
        out[(size_t)row * (NSTEPS * 512) + (size_t)s * 512 + col] = v;
    }
}

// ---------------- persistent kernel ------------------------------------------
__global__ __launch_bounds__(256, 1) void persist(
    const float* __restrict__ x,
    const ushort* __restrict__ wf0, const ushort* __restrict__ wf1,
    const ushort* __restrict__ wfO,
    const float* __restrict__ b_ih, const float* __restrict__ b_hh,
    const float* __restrict__ b_out,
    ushort* h0a, ushort* h0b, ushort* h1a, ushort* h1b,
    ushort* pred, float* out, unsigned* bar)
{
    __shared__ ushort sW[2][2][32][512];      // 128KB: [wn][prec][kfg][lane*8]
    __shared__ ushort sA[128][64];            // 16KB, XOR-swizzled chunks
    __shared__ float  cL[128][8];             // 4KB: this WG's c-state slice

    const int tid = threadIdx.x;
    const int blk = blockIdx.x;
    const int half = blk >> 7;
    const int w = blk & 127;
    const int mblk = w >> 6, hcblk = w & 63;

    {   // load this WG's weight slice (128KB, contiguous in the frag array)
        const uint4* srcv = (const uint4*)((half ? wf1 : wf0) + (size_t)hcblk * 65536);
        uint4* dstv = (uint4*)&sW[0][0][0][0];
        #pragma unroll 1
        for (int i = tid; i < 8192; i += 256) dstv[i] = srcv[i];
    }
    #pragma unroll
    for (int i = tid; i < 128 * 8; i += 256) ((float*)cL)[i] = 0.f;

    const int lane = tid & 63, wid = tid >> 6, wn = wid & 1;
    const int nloc = wn * 16 + (lane & 15);
    const int g = nloc & 3, hc = nloc >> 2;
    const int gcol = g * 512 + hcblk * 8 + hc;
    const float bias = b_ih[half * 2048 + gcol] + b_hh[half * 2048 + gcol];
    __syncthreads();

    ushort* h0buf[2] = {h0a, h0b};
    ushort* h1buf[2] = {h1a, h1b};
    unsigned nbar = 0;

    // ---- encode: 129 phases, layer-pipelined ----
    #pragma unroll 1
    for (int p = 0; p <= SS; ++p) {
        if (half == 0) {
            if (p < SS)
                run_cell(tid, mblk, hcblk, x + (size_t)p * 512, (size_t)(SS * 512), true,
                         h0buf[p & 1], sW, sA, cL, bias, h0buf[(p + 1) & 1]);
        } else {
            if (p >= 1) {
                int q = p - 1;
                run_cell(tid, mblk, hcblk, h0buf[p & 1], 512, false,
                         h1buf[q & 1], sW, sA, cL, bias, h1buf[(q + 1) & 1]);
            }
        }
        gridbar(bar, ++nbar);
    }
    int h0cur = 0, h1cur = 0;

    // ---- decode: fc -> L0 -> L1 serial ----
    #pragma unroll 1
    for (int s = 0; s < NSTEPS; ++s) {
        if (half == 0) run_fc(tid, w, h1buf[h1cur], wfO, b_out, pred, out, s);
        gridbar(bar, ++nbar);
        if (s == NSTEPS - 1) break;
        if (half == 0)
            run_cell(tid, mblk, hcblk, pred, 512, false,
                     h0buf[h0cur], sW, sA, cL, bias, h0buf[h0cur ^ 1]);
        gridbar(bar, ++nbar);
        h0cur ^= 1;
        if (half == 1)
            run_cell(tid, mblk, hcblk, h0buf[h0cur], 512, false,
                     h1buf[h1cur], sW, sA, cL, bias, h1buf[h1cur ^ 1]);
        gridbar(bar, ++nbar);
        h1cur ^= 1;
    }
}

// ---------------- host ---------------------------------------------------------
extern "C" void kernel_launch(void* const* d_in, const int* in_sizes, int n_in,
                              void* d_out, int out_size, void* d_ws, size_t ws_size,
                              hipStream_t stream)
{
    const float* x     = (const float*)d_in[0];
    const float* W_ih  = (const float*)d_in[1];
    const float* W_hh  = (const float*)d_in[2];
    const float* b_ih  = (const float*)d_in[3];
    const float* b_hh  = (const float*)d_in[4];
    const float* W_out = (const float*)d_in[5];
    const float* b_out = (const float*)d_in[6];
    float* out = (float*)d_out;
    (void)in_sizes; (void)n_in; (void)out_size; (void)ws_size;

    char* ws = (char*)d_ws;
    ushort* h0a  = (ushort*)(ws + 0);
    ushort* h0b  = (ushort*)(ws + 262144);
    ushort* h1a  = (ushort*)(ws + 524288);
    ushort* h1b  = (ushort*)(ws + 786432);
    ushort* pred = (ushort*)(ws + 1048576);
    unsigned* bar = (unsigned*)(ws + 2359296);
    const size_t ZBYTES = 2360320;            // states + barrier counters
    ushort* wf0 = (ushort*)(ws + 2360320);
    ushort* wf1 = (ushort*)(ws + 2360320 + 8388608);
    ushort* wfO = (ushort*)(ws + 2360320 + 2 * 8388608);
    // total ws use ≈ 20.2 MB

    hipMemsetAsync(d_ws, 0, ZBYTES, stream);
    wsplit_layers<<<2048, 256, 0, stream>>>(W_ih, W_hh, wf0, wf1);
    wsplit_out<<<128, 256, 0, stream>>>(W_out, wfO);

    // Regular launch: 148KB LDS -> 1 WG/CU; grid 256 = #CUs -> all co-resident.
    persist<<<dim3(256), dim3(256), 0, stream>>>(
        x, wf0, wf1, wfO, b_ih, b_hh, b_out,
        h0a, h0b, h1a, h1b, pred, out, bar);
}

// Round 6
// 5484.654 us; speedup vs baseline: 3.0418x; 1.1322x over previous
//
#include <hip/hip_runtime.h>
#include <math.h>

// TemporalDecoder round 6: pipelined persistent kernel.
// R5's per-iter __syncthreads drained vmcnt(0) -> every LLC load latency fully
// exposed (29us/phase vs ~2us compute). Now: raw s_barrier (no vmcnt drain),
// 2-deep register load pipeline (compiler-counted vmcnt at use), single barrier
// per K-iter via double-buffered sA, c-state in registers, 16x16 barrier tree.

#define BB 256
#define SS 128
#define HH 512
#define NSTEPS 32

typedef __attribute__((ext_vector_type(8))) _Float16 f16x8;
typedef __attribute__((ext_vector_type(4))) float f32x4;

#define LO_SCALE 2048.0f
#define LO_INV   (1.0f / 2048.0f)
#define AGENT __HIP_MEMORY_SCOPE_AGENT

__device__ __forceinline__ uint2 ld_agent_u2(const uint2* p) {
    return __hip_atomic_load(p, __ATOMIC_RELAXED, AGENT);
}
__device__ __forceinline__ void st_agent_h(ushort* p, ushort v) {
    __hip_atomic_store(p, v, __ATOMIC_RELAXED, AGENT);
}

// Raw WG barrier: LDS ordering only, leaves global loads in flight (no vmcnt drain).
__device__ __forceinline__ void wg_barrier() {
    __builtin_amdgcn_sched_barrier(0);
    asm volatile("s_waitcnt lgkmcnt(0)" ::: "memory");
    __builtin_amdgcn_s_barrier();
    asm volatile("" ::: "memory");
    __builtin_amdgcn_sched_barrier(0);
}

// ---------------- weight split kernels (fp32 -> f16 hi/lo, fragment order) ----
__global__ __launch_bounds__(256) void wsplit_layers(
    const float* __restrict__ W_ih, const float* __restrict__ W_hh,
    ushort* __restrict__ wf0, ushort* __restrict__ wf1)
{
    int f = blockIdx.x * 256 + threadIdx.x;      // 0..524287
    int L = f >> 18;
    int t = f & 262143;
    int lane = t & 63;
    int kfg = (t >> 6) & 31;
    int nfrag = t >> 11;                         // 0..127
    int nloc = (nfrag & 1) * 16 + (lane & 15);
    int g = nloc & 3, hc = nloc >> 2;
    int n_W = g * 512 + (nfrag >> 1) * 8 + hc;
    int mat = kfg >> 4;
    int klocal = (kfg & 15) * 32 + (lane >> 4) * 8;
    const float* src = (mat ? W_hh : W_ih) + (size_t)L * (2048 * 512)
                       + (size_t)n_W * 512 + klocal;
    float4 a = *(const float4*)src;
    float4 b = *(const float4*)(src + 4);
    float v[8] = {a.x, a.y, a.z, a.w, b.x, b.y, b.z, b.w};
    union { _Float16 h[8]; uint4 u; } Hi, Lo;
    #pragma unroll
    for (int j = 0; j < 8; ++j) {
        Hi.h[j] = (_Float16)v[j];
        Lo.h[j] = (_Float16)((v[j] - (float)Hi.h[j]) * LO_SCALE);
    }
    ushort* dst = L ? wf1 : wf0;
    size_t b0 = (((size_t)nfrag * 2 + 0) * 32 + kfg) * 512 + lane * 8;
    size_t b1 = (((size_t)nfrag * 2 + 1) * 32 + kfg) * 512 + lane * 8;
    *(uint4*)(dst + b0) = Hi.u;
    *(uint4*)(dst + b1) = Lo.u;
}

__global__ __launch_bounds__(256) void wsplit_out(
    const float* __restrict__ W_out, ushort* __restrict__ wfO)
{
    int f = blockIdx.x * 256 + threadIdx.x;      // 0..32767
    int lane = f & 63;
    int kfg = (f >> 6) & 15;
    int nfrag = f >> 10;                         // 0..31
    int n_W = nfrag * 16 + (lane & 15);
    int klocal = kfg * 32 + (lane >> 4) * 8;
    const float* src = W_out + (size_t)n_W * 512 + klocal;
    float4 a = *(const float4*)src;
    float4 b = *(const float4*)(src + 4);
    float v[8] = {a.x, a.y, a.z, a.w, b.x, b.y, b.z, b.w};
    union { _Float16 h[8]; uint4 u; } Hi, Lo;
    #pragma unroll
    for (int j = 0; j < 8; ++j) {
        Hi.h[j] = (_Float16)v[j];
        Lo.h[j] = (_Float16)((v[j] - (float)Hi.h[j]) * LO_SCALE);
    }
    size_t b0 = (((size_t)nfrag * 2 + 0) * 16 + kfg) * 512 + lane * 8;
    size_t b1 = (((size_t)nfrag * 2 + 1) * 16 + kfg) * 512 + lane * 8;
    *(uint4*)(wfO + b0) = Hi.u;
    *(uint4*)(wfO + b1) = Lo.u;
}

// ---------------- grid barrier (monotonic, 16 groups x 16 WGs, relaxed) -------
__device__ __forceinline__ void gridbar(unsigned* bar, unsigned phase)
{
    __syncthreads();   // full drain: this WG's h-stores complete before arrive
    if (threadIdx.x == 0) {
        const int grp = blockIdx.x & 15;
        unsigned* lc = bar + 16 + 16 * grp;      // 64B-spaced leaf counters
        unsigned* gc = bar;
        unsigned old = __hip_atomic_fetch_add(lc, 1u, __ATOMIC_RELAXED, AGENT);
        if (old == phase * 16u - 1u)             // last of 16 WGs in this group
            __hip_atomic_fetch_add(gc, 1u, __ATOMIC_RELAXED, AGENT);
        while (__hip_atomic_load(gc, __ATOMIC_RELAXED, AGENT) < phase * 16u)
            __builtin_amdgcn_s_sleep(1);
    }
    __syncthreads();
}

// ---------------- LSTM cell (one layer, M=128 x N=32 gate-cols, K=1024) -------
// Pipelined: 2-deep register prefetch of LLC loads, raw barriers (loads stay in
// flight), double-buffered sA, 1 barrier per K-iter. c-state in registers.
template<bool CVT>
static __device__ __forceinline__ void run_cell(
    const int tid, const int mblk, const int hcblk,
    const void* Asrc, const size_t ldA,
    const ushort* __restrict__ Hprev,
    ushort (*sW)[2][32][512], ushort (*sA)[128][64],
    float (&cReg)[16],
    const float bias, ushort* __restrict__ Hout)
{
    const int lane = tid & 63, wid = tid >> 6;
    const int wm = wid >> 1, wn = wid & 1;
    const int lr = lane & 15, lq = lane >> 4;

    f32x4 acch[4], accl[4];
    #pragma unroll
    for (int i = 0; i < 4; ++i) {
        acch[i] = (f32x4){bias, bias, bias, bias};
        accl[i] = (f32x4){0.f, 0.f, 0.f, 0.f};
    }

    const int srow = tid >> 1;               // 0..127
    const int cbase = (tid & 1) * 4;         // chunk base (chunks of 8 f16)
    uint2  ur[2][8];
    float4 fr[2][8];

    auto ld_coh = [&](int it, uint2* u) {
        const bool ph0 = (it < 8);
        const int k0 = (it & 7) * 64;
        const ushort* s = ph0
            ? ((const ushort*)Asrc + (size_t)(mblk * 128 + srow) * ldA + k0 + cbase * 8)
            : (Hprev + (size_t)(mblk * 128 + srow) * 512 + k0 + cbase * 8);
        const uint2* s2 = (const uint2*)s;
        #pragma unroll
        for (int c = 0; c < 8; ++c) u[c] = ld_agent_u2(s2 + c);
    };
    auto ld_cvt = [&](int it, float4* f) {
        const int k0 = (it & 7) * 64;
        const float* s = (const float*)Asrc
            + (size_t)(mblk * 128 + srow) * ldA + k0 + cbase * 8;
        #pragma unroll
        for (int c = 0; c < 4; ++c) {
            f[2 * c]     = *(const float4*)(s + c * 8);
            f[2 * c + 1] = *(const float4*)(s + c * 8 + 4);
        }
    };
    auto wr_ur = [&](const uint2* u, ushort (*dst)[64]) {
        #pragma unroll
        for (int c = 0; c < 4; ++c) {
            uint4 wv;
            wv.x = u[2 * c].x;     wv.y = u[2 * c].y;
            wv.z = u[2 * c + 1].x; wv.w = u[2 * c + 1].y;
            *(uint4*)&dst[srow][((cbase + c) ^ (srow & 7)) * 8] = wv;
        }
    };
    auto wr_fr = [&](const float4* f, ushort (*dst)[64]) {
        #pragma unroll
        for (int c = 0; c < 4; ++c) {
            union { _Float16 h[8]; uint4 u; } P;
            const float4 f0 = f[2 * c], f1 = f[2 * c + 1];
            P.h[0] = (_Float16)f0.x; P.h[1] = (_Float16)f0.y;
            P.h[2] = (_Float16)f0.z; P.h[3] = (_Float16)f0.w;
            P.h[4] = (_Float16)f1.x; P.h[5] = (_Float16)f1.y;
            P.h[6] = (_Float16)f1.z; P.h[7] = (_Float16)f1.w;
            *(uint4*)&dst[srow][((cbase + c) ^ (srow & 7)) * 8] = P.u;
        }
    };
    auto compute = [&](int it) {
        ushort (*buf)[64] = sA[it & 1];
        #pragma unroll
        for (int kf = 0; kf < 2; ++kf) {
            const int kfg = it * 2 + kf;
            const f16x8 bh = *(const f16x8*)&sW[wn][0][kfg][lane * 8];
            const f16x8 bl = *(const f16x8*)&sW[wn][1][kfg][lane * 8];
            #pragma unroll
            for (int mf = 0; mf < 4; ++mf) {
                const int row = wm * 64 + mf * 16 + lr;
                const int cg = kf * 4 + lq;
                const f16x8 a = *(const f16x8*)&buf[row][(cg ^ (row & 7)) * 8];
                acch[mf] = __builtin_amdgcn_mfma_f32_16x16x32_f16(a, bh, acch[mf], 0, 0, 0);
                accl[mf] = __builtin_amdgcn_mfma_f32_16x16x32_f16(a, bl, accl[mf], 0, 0, 0);
            }
        }
    };

    // prologue: loads for it=0,1 in flight; write it=0
    if constexpr (CVT) {
        ld_cvt(0, fr[0]); ld_cvt(1, fr[1]); wr_fr(fr[0], sA[0]);
    } else {
        ld_coh(0, ur[0]); ld_coh(1, ur[1]); wr_ur(ur[0], sA[0]);
    }

    #pragma unroll
    for (int it = 0; it < 16; ++it) {
        wg_barrier();                       // sA[it&1] ready; loads stay in flight
        if (it + 2 < 16) {                  // issue loads for it+2 into slot it&1
            if (CVT && (it + 2) < 8) ld_cvt(it + 2, fr[it & 1]);
            else                     ld_coh(it + 2, ur[it & 1]);
        }
        if (it + 1 < 16) {                  // write it+1 (compiler-counted vmcnt wait)
            if (CVT && (it + 1) < 8) wr_fr(fr[(it + 1) & 1], sA[(it + 1) & 1]);
            else                     wr_ur(ur[(it + 1) & 1], sA[(it + 1) & 1]);
        }
        compute(it);
    }

    // epilogue: gather i,f,g,o across the 4-lane group, apply cell
    const int nloc = wn * 16 + lr;
    const int g = nloc & 3, hc = nloc >> 2;
    const int hcol = hcblk * 8 + hc;
    #pragma unroll
    for (int mf = 0; mf < 4; ++mf) {
        #pragma unroll
        for (int j = 0; j < 4; ++j) {
            float v = acch[mf][j] + accl[mf][j] * LO_INV;
            float s1 = __shfl_xor(v, 1, 64);
            float s2 = __shfl_xor(v, 2, 64);
            float s3 = __shfl_xor(v, 3, 64);
            float sel0 = v;
            auto selk = [&](int k) {
                return (k == 0) ? sel0 : (k == 1) ? s1 : (k == 2) ? s2 : s3;
            };
            float pi = selk(g), pf = selk(g ^ 1), pg = selk(g ^ 2), po = selk(g ^ 3);
            int row = mblk * 128 + wm * 64 + mf * 16 + lq * 4 + j;
            float ig = 1.f / (1.f + __expf(-pi));
            float fg = 1.f / (1.f + __expf(-pf));
            float e2g = __expf(2.f * fminf(fmaxf(pg, -20.f), 20.f));
            float gg = (e2g - 1.f) / (e2g + 1.f);
            float og = 1.f / (1.f + __expf(-po));
            if (g == 0) {
                float cn = fg * cReg[mf * 4 + j] + ig * gg;
                cReg[mf * 4 + j] = cn;
                float e2c = __expf(2.f * fminf(fmaxf(cn, -20.f), 20.f));
                float th = (e2c - 1.f) / (e2c + 1.f);
                float hn = og * th;
                union { _Float16 h; ushort u; } P;
                P.h = (_Float16)hn;
                st_agent_h(&Hout[(size_t)row * 512 + hcol], P.u);
            }
        }
    }
}

// ---------------- fc: pred = h1 @ Wout^T + b_out (half0 WGs only) -------------
static __device__ __forceinline__ void run_fc(
    const int tid, const int w,
    const ushort* __restrict__ h1, const ushort* __restrict__ wfO,
    const float* __restrict__ b_out,
    ushort* __restrict__ pred, float* __restrict__ out, const int s)
{
    const int lane = tid & 63, wid = tid >> 6;
    const int wm = wid >> 1, wn = wid & 1;
    const int lr = lane & 15, lq = lane >> 4;
    const int fm = w & 7, fn = w >> 3;        // 8 m-blocks x 16 n-blocks
    const int nfrag = fn * 2 + wn;
    const int col = nfrag * 16 + lr;
    const int arow = fm * 32 + wm * 16 + lr;

    float bv = b_out[col];
    f32x4 acch = (f32x4){bv, bv, bv, bv};
    f32x4 accl = (f32x4){0.f, 0.f, 0.f, 0.f};

    uint2 au[32];
    #pragma unroll
    for (int kfg = 0; kfg < 16; ++kfg) {
        const uint2* s = (const uint2*)&h1[(size_t)arow * 512 + kfg * 32 + lq * 8];
        au[2 * kfg]     = ld_agent_u2(s);
        au[2 * kfg + 1] = ld_agent_u2(s + 1);
    }
    #pragma unroll
    for (int kfg = 0; kfg < 16; ++kfg) {
        union { uint2 u[2]; f16x8 v; } A;
        A.u[0] = au[2 * kfg]; A.u[1] = au[2 * kfg + 1];
        const f16x8 bh = *(const f16x8*)&wfO[(((size_t)nfrag * 2 + 0) * 16 + kfg) * 512 + lane * 8];
        const f16x8 bl = *(const f16x8*)&wfO[(((size_t)nfrag * 2 + 1) * 16 + kfg) * 512 + lane * 8];
        acch = __builtin_amdgcn_mfma_f32_16x16x32_f16(A.v, bh, acch, 0, 0, 0);
        accl = __builtin_amdgcn_mfma_f32_16x16x32_f16(A.v, bl, accl, 0, 0, 0);
    }
    #pragma unroll
    for (int j = 0; j < 4; ++j) {
        float v = acch[j] + accl[j] * LO_INV;
        int row = fm * 32 + wm * 16 + lq * 4 + j;
        union { _Float16 h; ushort u; } P;
        P.h = (_Float16)v;
        st_agent_h(&pred[(size_t)row * 512 + col], P.u);
        out[(size_t)row * (NSTEPS * 512) + (size_t)s * 512 + col] = v;
    }
}

// ---------------- persistent kernel ------------------------------------------
__global__ __launch_bounds__(256, 1) void persist(
    const float* __restrict__ x,
    const ushort* __restrict__ wf0, const ushort* __restrict__ wf1,
    const ushort* __restrict__ wfO,
    const float* __restrict__ b_ih, const float* __restrict__ b_hh,
    const float* __restrict__ b_out,
    ushort* h0a, ushort* h0b, ushort* h1a, ushort* h1b,
    ushort* pred, float* out, unsigned* bar)
{
    __shared__ ushort sW[2][2][32][512];      // 128KB: [wn][prec][kfg][lane*8]
    __shared__ ushort sA[2][128][64];         // 32KB, double-buffered, swizzled

    const int tid = threadIdx.x;
    const int blk = blockIdx.x;
    const int half = blk >> 7;
    const int w = blk & 127;
    const int mblk = w >> 6, hcblk = w & 63;

    {   // load this WG's weight slice (128KB, contiguous in the frag array)
        const uint4* srcv = (const uint4*)((half ? wf1 : wf0) + (size_t)hcblk * 65536);
        uint4* dstv = (uint4*)&sW[0][0][0][0];
        #pragma unroll 1
        for (int i = tid; i < 8192; i += 256) dstv[i] = srcv[i];
    }

    float cReg[16];
    #pragma unroll
    for (int i = 0; i < 16; ++i) cReg[i] = 0.f;

    const int lane = tid & 63, wid = tid >> 6, wn = wid & 1;
    const int nloc = wn * 16 + (lane & 15);
    const int g = nloc & 3, hc = nloc >> 2;
    const int gcol = g * 512 + hcblk * 8 + hc;
    const float bias = b_ih[half * 2048 + gcol] + b_hh[half * 2048 + gcol];
    __syncthreads();

    ushort* h0buf[2] = {h0a, h0b};
    ushort* h1buf[2] = {h1a, h1b};
    unsigned nbar = 0;

    // ---- encode: 129 phases, layer-pipelined ----
    #pragma unroll 1
    for (int p = 0; p <= SS; ++p) {
        if (half == 0) {
            if (p < SS)
                run_cell<true>(tid, mblk, hcblk, x + (size_t)p * 512, (size_t)(SS * 512),
                               h0buf[p & 1], sW, sA, cReg, bias, h0buf[(p + 1) & 1]);
        } else {
            if (p >= 1) {
                int q = p - 1;
                run_cell<false>(tid, mblk, hcblk, h0buf[p & 1], 512,
                                h1buf[q & 1], sW, sA, cReg, bias, h1buf[(q + 1) & 1]);
            }
        }
        gridbar(bar, ++nbar);
    }
    int h0cur = 0, h1cur = 0;

    // ---- decode: fc -> L0 -> L1 serial ----
    #pragma unroll 1
    for (int s = 0; s < NSTEPS; ++s) {
        if (half == 0) run_fc(tid, w, h1buf[h1cur], wfO, b_out, pred, out, s);
        gridbar(bar, ++nbar);
        if (s == NSTEPS - 1) break;
        if (half == 0)
            run_cell<false>(tid, mblk, hcblk, pred, 512,
                            h0buf[h0cur], sW, sA, cReg, bias, h0buf[h0cur ^ 1]);
        gridbar(bar, ++nbar);
        h0cur ^= 1;
        if (half == 1)
            run_cell<false>(tid, mblk, hcblk, h0buf[h0cur], 512,
                            h1buf[h1cur], sW, sA, cReg, bias, h1buf[h1cur ^ 1]);
        gridbar(bar, ++nbar);
        h1cur ^= 1;
    }
}

// ---------------- host ---------------------------------------------------------
extern "C" void kernel_launch(void* const* d_in, const int* in_sizes, int n_in,
                              void* d_out, int out_size, void* d_ws, size_t ws_size,
                              hipStream_t stream)
{
    const float* x     = (const float*)d_in[0];
    const float* W_ih  = (const float*)d_in[1];
    const float* W_hh  = (const float*)d_in[2];
    const float* b_ih  = (const float*)d_in[3];
    const float* b_hh  = (const float*)d_in[4];
    const float* W_out = (const float*)d_in[5];
    const float* b_out = (const float*)d_in[6];
    float* out = (float*)d_out;
    (void)in_sizes; (void)n_in; (void)out_size; (void)ws_size;

    char* ws = (char*)d_ws;
    ushort* h0a  = (ushort*)(ws + 0);
    ushort* h0b  = (ushort*)(ws + 262144);
    ushort* h1a  = (ushort*)(ws + 524288);
    ushort* h1b  = (ushort*)(ws + 786432);
    ushort* pred = (ushort*)(ws + 1048576);
    unsigned* bar = (unsigned*)(ws + 2359296);
    const size_t ZBYTES = 2361344;            // states + barrier counters
    ushort* wf0 = (ushort*)(ws + 2361344);
    ushort* wf1 = (ushort*)(ws + 2361344 + 8388608);
    ushort* wfO = (ushort*)(ws + 2361344 + 2 * 8388608);
    // total ws use ~20.2 MB

    hipMemsetAsync(d_ws, 0, ZBYTES, stream);
    wsplit_layers<<<2048, 256, 0, stream>>>(W_ih, W_hh, wf0, wf1);
    wsplit_out<<<128, 256, 0, stream>>>(W_out, wfO);

    // Regular launch: 160KB LDS -> 1 WG/CU; grid 256 = #CUs -> all co-resident.
    persist<<<dim3(256), dim3(256), 0, stream>>>(
        x, wf0, wf1, wfO, b_ih, b_hh, b_out,
        h0a, h0b, h1a, h1b, pred, out, bar);
}